// Round 1
// baseline (2109.265 us; speedup 1.0000x reference)
//
#include <hip/hip_runtime.h>
#include <hip/hip_bf16.h>
#include <math.h>

// Problem constants (fixed by setup_inputs)
#define M_SEG 128
#define S_SEG 512
#define HD 512
#define NHEAD 8
#define DHEAD 64
#define NROWS (M_SEG * S_SEG)   // 65536
#define GAMMA_F 0.96875f
#define SCALE_F 0.125f          // d^-0.5 = 64^-0.5

// ---------------------------------------------------------------------------
// GEMM NT: C[n,i] = sum_j A[n,j] * B[i,j]   A: NROWS x 512, B: 512 x 512
// EPI==1: C is d_out; writes row n+1 = acc + X[n,:] + bias
// ---------------------------------------------------------------------------
template<int EPI>
__global__ __launch_bounds__(256) void gemm_nt(const float* __restrict__ A,
                                               const float* __restrict__ B,
                                               float* __restrict__ C,
                                               const float* __restrict__ X,
                                               const float* __restrict__ bias)
{
    __shared__ __align__(16) float As[32][68];
    __shared__ __align__(16) float Bs[32][68];
    const int t = threadIdx.x;
    const int cBase = blockIdx.x * 64;   // output col tile (8 tiles)
    const int nBase = blockIdx.y * 64;   // row tile (1024 tiles)
    const int tm = (t >> 4) * 4;
    const int tn = (t & 15) * 4;
    float acc[4][4] = {};

    for (int k0 = 0; k0 < HD; k0 += 32) {
#pragma unroll
        for (int i = 0; i < 2; ++i) {
            int lin = t + i * 256;      // 0..511 : 64 rows x 8 float4
            int row = lin >> 3;
            int kq  = lin & 7;
            float4 a4 = *reinterpret_cast<const float4*>(&A[(size_t)(nBase + row) * HD + k0 + kq * 4]);
            As[kq * 4 + 0][row] = a4.x;
            As[kq * 4 + 1][row] = a4.y;
            As[kq * 4 + 2][row] = a4.z;
            As[kq * 4 + 3][row] = a4.w;
            float4 b4 = *reinterpret_cast<const float4*>(&B[(size_t)(cBase + row) * HD + k0 + kq * 4]);
            Bs[kq * 4 + 0][row] = b4.x;
            Bs[kq * 4 + 1][row] = b4.y;
            Bs[kq * 4 + 2][row] = b4.z;
            Bs[kq * 4 + 3][row] = b4.w;
        }
        __syncthreads();
#pragma unroll
        for (int kk = 0; kk < 32; ++kk) {
            float4 a4 = *reinterpret_cast<const float4*>(&As[kk][tm]);
            float4 b4 = *reinterpret_cast<const float4*>(&Bs[kk][tn]);
            float av[4] = {a4.x, a4.y, a4.z, a4.w};
            float bv[4] = {b4.x, b4.y, b4.z, b4.w};
#pragma unroll
            for (int i = 0; i < 4; ++i)
#pragma unroll
                for (int j = 0; j < 4; ++j)
                    acc[i][j] = fmaf(av[i], bv[j], acc[i][j]);
        }
        __syncthreads();
    }

#pragma unroll
    for (int i = 0; i < 4; ++i) {
        const int n = nBase + tm + i;
        const int c = cBase + tn;
        if (EPI == 1) {
            float4 x4 = *reinterpret_cast<const float4*>(&X[(size_t)n * HD + c]);
            float4 b4 = *reinterpret_cast<const float4*>(&bias[c]);
            float4 o;
            o.x = acc[i][0] + x4.x + b4.x;
            o.y = acc[i][1] + x4.y + b4.y;
            o.z = acc[i][2] + x4.z + b4.z;
            o.w = acc[i][3] + x4.w + b4.w;
            *reinterpret_cast<float4*>(&C[(size_t)(n + 1) * HD + c]) = o;
        } else {
            float4 o = make_float4(acc[i][0], acc[i][1], acc[i][2], acc[i][3]);
            *reinterpret_cast<float4*>(&C[(size_t)n * HD + c]) = o;
        }
    }
}

// ---------------------------------------------------------------------------
// A[m,h,d,e] = sum_s k[m*S+s, h*64+d] * v[m*S+s, h*64+e]
// ---------------------------------------------------------------------------
__global__ __launch_bounds__(256) void kv_outer(const float* __restrict__ kmat,
                                                const float* __restrict__ vmat,
                                                float* __restrict__ Abuf)
{
    __shared__ __align__(16) float Ks[32][68];
    __shared__ __align__(16) float Vs[32][68];
    const int t = threadIdx.x;
    const int hh = blockIdx.x;
    const int m  = blockIdx.y;
    const int td = (t >> 4) * 4;
    const int te = (t & 15) * 4;
    float acc[4][4] = {};

    for (int s0 = 0; s0 < S_SEG; s0 += 32) {
#pragma unroll
        for (int i = 0; i < 2; ++i) {
            int lin = t + i * 256;      // 32 rows x 16 float4
            int sl = lin >> 4;
            int cq = lin & 15;
            size_t gidx = (size_t)(m * S_SEG + s0 + sl) * HD + hh * DHEAD + cq * 4;
            *reinterpret_cast<float4*>(&Ks[sl][cq * 4]) = *reinterpret_cast<const float4*>(&kmat[gidx]);
            *reinterpret_cast<float4*>(&Vs[sl][cq * 4]) = *reinterpret_cast<const float4*>(&vmat[gidx]);
        }
        __syncthreads();
#pragma unroll
        for (int sl = 0; sl < 32; ++sl) {
            float4 a4 = *reinterpret_cast<const float4*>(&Ks[sl][td]);
            float4 b4 = *reinterpret_cast<const float4*>(&Vs[sl][te]);
            float av[4] = {a4.x, a4.y, a4.z, a4.w};
            float bv[4] = {b4.x, b4.y, b4.z, b4.w};
#pragma unroll
            for (int i = 0; i < 4; ++i)
#pragma unroll
                for (int j = 0; j < 4; ++j)
                    acc[i][j] = fmaf(av[i], bv[j], acc[i][j]);
        }
        __syncthreads();
    }

#pragma unroll
    for (int i = 0; i < 4; ++i) {
        size_t base = ((size_t)(m * NHEAD + hh) * DHEAD + td + i) * DHEAD + te;
        *reinterpret_cast<float4*>(&Abuf[base]) = make_float4(acc[i][0], acc[i][1], acc[i][2], acc[i][3]);
    }
}

// ---------------------------------------------------------------------------
// r_m = A_m + decay*r_{m-1} ;  Bc_m = scale*A_m + gamma^{m+1} * r_m
// ---------------------------------------------------------------------------
__global__ __launch_bounds__(256) void scan_kernel(const float* __restrict__ Abuf,
                                                   float* __restrict__ Bc)
{
    const int tid = blockIdx.x * 256 + threadIdx.x;   // 0..32767
    const float decay = powf(GAMMA_F, (float)S_SEG);
    float r = 0.0f;
    float g = 1.0f;
    for (int m = 0; m < M_SEG; ++m) {
        float a = Abuf[(size_t)m * 32768 + tid];
        r = fmaf(decay, r, a);
        g *= GAMMA_F;                  // gamma^(m+1)
        Bc[(size_t)m * 32768 + tid] = fmaf(g, r, SCALE_F * a);
    }
}

// ---------------------------------------------------------------------------
// h[m,s,hh*64+e] = relu( sum_d q[m,s,hh*64+d] * Bc[m,hh,d,e] )
// ---------------------------------------------------------------------------
__global__ __launch_bounds__(256) void h_kernel(const float* __restrict__ q,
                                                const float* __restrict__ Bc,
                                                float* __restrict__ hbuf)
{
    __shared__ __align__(16) float QsT[64][68];   // [d][row]
    __shared__ __align__(16) float BcS[64][68];   // [d][e]
    const int t = threadIdx.x;
    const int s0 = blockIdx.x * 64;
    const int m  = blockIdx.y;
    const int tr = (t >> 4) * 4;
    const int tc = (t & 15) * 4;

    for (int hh = 0; hh < NHEAD; ++hh) {
#pragma unroll
        for (int i = 0; i < 4; ++i) {
            int lin = t + i * 256;     // 0..1023 : 64 rows x 16 float4
            int r = lin >> 4;
            int cq = lin & 15;
            float4 a4 = *reinterpret_cast<const float4*>(
                &q[(size_t)(m * S_SEG + s0 + r) * HD + hh * DHEAD + cq * 4]);
            QsT[cq * 4 + 0][r] = a4.x;
            QsT[cq * 4 + 1][r] = a4.y;
            QsT[cq * 4 + 2][r] = a4.z;
            QsT[cq * 4 + 3][r] = a4.w;
            float4 b4 = *reinterpret_cast<const float4*>(
                &Bc[(size_t)(m * NHEAD + hh) * 4096 + lin * 4]);
            *reinterpret_cast<float4*>(&BcS[r][cq * 4]) = b4;
        }
        __syncthreads();

        float acc[4][4] = {};
#pragma unroll
        for (int dd = 0; dd < 64; ++dd) {
            float4 a4 = *reinterpret_cast<const float4*>(&QsT[dd][tr]);
            float4 b4 = *reinterpret_cast<const float4*>(&BcS[dd][tc]);
            float av[4] = {a4.x, a4.y, a4.z, a4.w};
            float bv[4] = {b4.x, b4.y, b4.z, b4.w};
#pragma unroll
            for (int i = 0; i < 4; ++i)
#pragma unroll
                for (int j = 0; j < 4; ++j)
                    acc[i][j] = fmaf(av[i], bv[j], acc[i][j]);
        }

#pragma unroll
        for (int i = 0; i < 4; ++i) {
            float4 o;
            o.x = fmaxf(acc[i][0], 0.0f);
            o.y = fmaxf(acc[i][1], 0.0f);
            o.z = fmaxf(acc[i][2], 0.0f);
            o.w = fmaxf(acc[i][3], 0.0f);
            *reinterpret_cast<float4*>(
                &hbuf[(size_t)(m * S_SEG + s0 + tr + i) * HD + hh * DHEAD + tc]) = o;
        }
        __syncthreads();
    }
}

// ---------------------------------------------------------------------------
// GroupNorm over (S, 64) per (m, group), in place on d_out rows 1..N
// ---------------------------------------------------------------------------
__global__ __launch_bounds__(256) void groupnorm_kernel(float* __restrict__ out,
                                                        const float* __restrict__ gn_w,
                                                        const float* __restrict__ gn_b)
{
    const int g = blockIdx.x;
    const int m = blockIdx.y;
    const int t = threadIdx.x;
    float* base = out + (size_t)(1 + m * S_SEG) * HD + g * DHEAD;

    float sum = 0.0f, sq = 0.0f;
    for (int idx = t; idx < 8192; idx += 256) {     // 512 rows x 16 float4
        int s = idx >> 4;
        int cq = idx & 15;
        float4 v = *reinterpret_cast<const float4*>(&base[(size_t)s * HD + cq * 4]);
        sum += v.x + v.y + v.z + v.w;
        sq  += v.x * v.x + v.y * v.y + v.z * v.z + v.w * v.w;
    }
    __shared__ float rs[256], rq[256];
    rs[t] = sum; rq[t] = sq;
    __syncthreads();
    for (int off = 128; off > 0; off >>= 1) {
        if (t < off) { rs[t] += rs[t + off]; rq[t] += rq[t + off]; }
        __syncthreads();
    }
    __shared__ float smean, sinv;
    if (t == 0) {
        float mean = rs[0] * (1.0f / 32768.0f);
        float var  = rq[0] * (1.0f / 32768.0f) - mean * mean;
        smean = mean;
        sinv  = rsqrtf(var + 1e-5f);
    }
    __syncthreads();
    const float mean = smean, inv = sinv;

    for (int idx = t; idx < 8192; idx += 256) {
        int s = idx >> 4;
        int cq = idx & 15;
        float4 v = *reinterpret_cast<const float4*>(&base[(size_t)s * HD + cq * 4]);
        float4 w4 = *reinterpret_cast<const float4*>(&gn_w[g * DHEAD + cq * 4]);
        float4 b4 = *reinterpret_cast<const float4*>(&gn_b[g * DHEAD + cq * 4]);
        v.x = (v.x - mean) * inv * w4.x + b4.x;
        v.y = (v.y - mean) * inv * w4.y + b4.y;
        v.z = (v.z - mean) * inv * w4.z + b4.z;
        v.w = (v.w - mean) * inv * w4.w + b4.w;
        *reinterpret_cast<float4*>(&base[(size_t)s * HD + cq * 4]) = v;
    }
}

__global__ void zero_row(float* __restrict__ out)
{
    int i = blockIdx.x * 256 + threadIdx.x;
    if (i < HD) out[i] = 0.0f;
}

// ---------------------------------------------------------------------------
extern "C" void kernel_launch(void* const* d_in, const int* in_sizes, int n_in,
                              void* d_out, int out_size, void* d_ws, size_t ws_size,
                              hipStream_t stream)
{
    const float* msg = (const float*)d_in[0];
    const float* Wq  = (const float*)d_in[1];
    const float* Wk  = (const float*)d_in[2];
    const float* Wv  = (const float*)d_in[3];
    const float* Wo  = (const float*)d_in[4];
    const float* bo  = (const float*)d_in[5];
    const float* gnw = (const float*)d_in[6];
    const float* gnb = (const float*)d_in[7];
    float* out = (float*)d_out;

    float* buf0 = (float*)d_ws;                 // k, then q
    float* buf1 = buf0 + (size_t)NROWS * HD;    // v, then h
    // A / Bc scratch live in d_out's first 33.6 MB; both fully consumed
    // before the output GEMM starts writing d_out (stream-ordered).
    float* Abuf = out;                          // 128*8*64*64 = 4194304 floats
    float* Bc   = out + 4194304;

    dim3 gemmGrid(HD / 64, NROWS / 64);

    gemm_nt<0><<<gemmGrid, 256, 0, stream>>>(msg, Wk, buf0, nullptr, nullptr);
    gemm_nt<0><<<gemmGrid, 256, 0, stream>>>(msg, Wv, buf1, nullptr, nullptr);
    kv_outer<<<dim3(NHEAD, M_SEG), 256, 0, stream>>>(buf0, buf1, Abuf);
    scan_kernel<<<128, 256, 0, stream>>>(Abuf, Bc);
    gemm_nt<0><<<gemmGrid, 256, 0, stream>>>(msg, Wq, buf0, nullptr, nullptr);
    h_kernel<<<dim3(S_SEG / 64, M_SEG), 256, 0, stream>>>(buf0, Bc, buf1);
    gemm_nt<1><<<gemmGrid, 256, 0, stream>>>(buf1, Wo, out, msg, bo);
    zero_row<<<2, 256, 0, stream>>>(out);
    groupnorm_kernel<<<dim3(NHEAD, M_SEG), 256, 0, stream>>>(out, gnw, gnb);
}

// Round 2
// 482.568 us; speedup vs baseline: 4.3709x; 4.3709x over previous
//
#include <hip/hip_runtime.h>
#include <math.h>

// Problem constants (fixed by setup_inputs)
#define M_SEG 128
#define S_SEG 512
#define HD 512
#define NHEAD 8
#define DHEAD 64
#define NROWS (M_SEG * S_SEG)   // 65536
#define GAMMA_F 0.96875f
#define SCALE_F 0.125f          // d^-0.5

typedef unsigned short u16;
typedef float f32x4 __attribute__((ext_vector_type(4)));
typedef __bf16 bf16x8 __attribute__((ext_vector_type(8)));
typedef unsigned short ushort8 __attribute__((ext_vector_type(8)));

__device__ __forceinline__ u16 f2bf(float f) {
    union { float f; unsigned u; } x; x.f = f;
    unsigned r = x.u + 0x7FFFu + ((x.u >> 16) & 1u);   // RNE
    return (u16)(r >> 16);
}

// ---------------------------------------------------------------------------
// fp32 -> bf16 conversion, 8 elems/thread
// ---------------------------------------------------------------------------
__global__ __launch_bounds__(256) void convert_bf16(const float* __restrict__ in,
                                                    u16* __restrict__ outp, int n8)
{
    int idx = blockIdx.x * 256 + threadIdx.x;
    if (idx >= n8) return;
    const float4 a = *reinterpret_cast<const float4*>(&in[(size_t)idx * 8]);
    const float4 b = *reinterpret_cast<const float4*>(&in[(size_t)idx * 8 + 4]);
    ushort8 o;
    o[0] = f2bf(a.x); o[1] = f2bf(a.y); o[2] = f2bf(a.z); o[3] = f2bf(a.w);
    o[4] = f2bf(b.x); o[5] = f2bf(b.y); o[6] = f2bf(b.z); o[7] = f2bf(b.w);
    *reinterpret_cast<ushort8*>(&outp[(size_t)idx * 8]) = o;
}

// ---------------------------------------------------------------------------
// bf16 MFMA GEMM NT: C[n,i] = sum_j A[n,j]*B[i,j]; A: 65536x512, B: 512x512
// 128x128 tile, BK=32, 4 waves (2x2 of 64x64), 16x16x32 MFMA.
// LDS slot-swizzle: slot = kc ^ ((row>>1)&3)  -> 2-way banks on rd & wr.
// EPI==0: C bf16. EPI==1: C=d_out fp32, row n+1 = acc + X[n,:] + bias.
// ---------------------------------------------------------------------------
template<int EPI>
__global__ __launch_bounds__(256) void gemm_bf16(const u16* __restrict__ A,
                                                 const u16* __restrict__ B,
                                                 void* __restrict__ Cv,
                                                 const float* __restrict__ X,
                                                 const float* __restrict__ bias)
{
    __shared__ __align__(16) u16 As[128 * 32];
    __shared__ __align__(16) u16 Bs[128 * 32];
    const int t    = threadIdx.x;
    const int lane = t & 63;
    const int w    = t >> 6;
    const int wr   = (w >> 1) * 64;
    const int wc   = (w & 1) * 64;

    // XCD-bijective swizzle: nwg = 2048, 2048 % 8 == 0
    const int bid  = blockIdx.x;
    const int sbid = (bid & 7) * 256 + (bid >> 3);
    const int rowBase = (sbid >> 2) * 128;
    const int colBase = (sbid & 3) * 128;

    const int frow = lane & 15;
    const int fkc  = lane >> 4;

    const int srow0 = t >> 2;          // rows 0..63
    const int srow1 = srow0 + 64;      // rows 64..127
    const int skc   = t & 3;
    const int slot0 = skc ^ ((srow0 >> 1) & 3);
    const int slot1 = skc ^ ((srow1 >> 1) & 3);

    f32x4 acc[4][4];
#pragma unroll
    for (int i = 0; i < 4; ++i)
#pragma unroll
        for (int j = 0; j < 4; ++j)
            acc[i][j] = (f32x4){0.f, 0.f, 0.f, 0.f};

    bf16x8 ra0, ra1, rb0, rb1;
    ra0 = *reinterpret_cast<const bf16x8*>(&A[(size_t)(rowBase + srow0) * HD + skc * 8]);
    ra1 = *reinterpret_cast<const bf16x8*>(&A[(size_t)(rowBase + srow1) * HD + skc * 8]);
    rb0 = *reinterpret_cast<const bf16x8*>(&B[(size_t)(colBase + srow0) * HD + skc * 8]);
    rb1 = *reinterpret_cast<const bf16x8*>(&B[(size_t)(colBase + srow1) * HD + skc * 8]);
    *reinterpret_cast<bf16x8*>(&As[srow0 * 32 + slot0 * 8]) = ra0;
    *reinterpret_cast<bf16x8*>(&As[srow1 * 32 + slot1 * 8]) = ra1;
    *reinterpret_cast<bf16x8*>(&Bs[srow0 * 32 + slot0 * 8]) = rb0;
    *reinterpret_cast<bf16x8*>(&Bs[srow1 * 32 + slot1 * 8]) = rb1;
    __syncthreads();

    for (int ks = 0; ks < 16; ++ks) {
        if (ks < 15) {
            const int k0 = (ks + 1) * 32;
            ra0 = *reinterpret_cast<const bf16x8*>(&A[(size_t)(rowBase + srow0) * HD + k0 + skc * 8]);
            ra1 = *reinterpret_cast<const bf16x8*>(&A[(size_t)(rowBase + srow1) * HD + k0 + skc * 8]);
            rb0 = *reinterpret_cast<const bf16x8*>(&B[(size_t)(colBase + srow0) * HD + k0 + skc * 8]);
            rb1 = *reinterpret_cast<const bf16x8*>(&B[(size_t)(colBase + srow1) * HD + k0 + skc * 8]);
        }
        bf16x8 af[4], bfr[4];
#pragma unroll
        for (int mm = 0; mm < 4; ++mm) {
            const int rA = wr + mm * 16 + frow;
            af[mm]  = *reinterpret_cast<const bf16x8*>(&As[rA * 32 + (fkc ^ ((rA >> 1) & 3)) * 8]);
            const int rB = wc + mm * 16 + frow;
            bfr[mm] = *reinterpret_cast<const bf16x8*>(&Bs[rB * 32 + (fkc ^ ((rB >> 1) & 3)) * 8]);
        }
#pragma unroll
        for (int mm = 0; mm < 4; ++mm)
#pragma unroll
            for (int nn = 0; nn < 4; ++nn)
                acc[mm][nn] = __builtin_amdgcn_mfma_f32_16x16x32_bf16(af[mm], bfr[nn], acc[mm][nn], 0, 0, 0);
        __syncthreads();
        if (ks < 15) {
            *reinterpret_cast<bf16x8*>(&As[srow0 * 32 + slot0 * 8]) = ra0;
            *reinterpret_cast<bf16x8*>(&As[srow1 * 32 + slot1 * 8]) = ra1;
            *reinterpret_cast<bf16x8*>(&Bs[srow0 * 32 + slot0 * 8]) = rb0;
            *reinterpret_cast<bf16x8*>(&Bs[srow1 * 32 + slot1 * 8]) = rb1;
            __syncthreads();
        }
    }

    const int orow = (lane >> 4) * 4;   // C/D: row=(lane>>4)*4+reg, col=lane&15
    if (EPI == 0) {
        u16* C = (u16*)Cv;
#pragma unroll
        for (int mm = 0; mm < 4; ++mm)
#pragma unroll
            for (int nn = 0; nn < 4; ++nn) {
                const int col  = colBase + wc + nn * 16 + frow;
                const int row0 = rowBase + wr + mm * 16 + orow;
#pragma unroll
                for (int r = 0; r < 4; ++r)
                    C[(size_t)(row0 + r) * HD + col] = f2bf(acc[mm][nn][r]);
            }
    } else {
        float* C = (float*)Cv;
#pragma unroll
        for (int mm = 0; mm < 4; ++mm)
#pragma unroll
            for (int nn = 0; nn < 4; ++nn) {
                const int col  = colBase + wc + nn * 16 + frow;
                const int row0 = rowBase + wr + mm * 16 + orow;
#pragma unroll
                for (int r = 0; r < 4; ++r) {
                    const int n = row0 + r;
                    C[(size_t)(n + 1) * HD + col] =
                        acc[mm][nn][r] + X[(size_t)n * HD + col] + bias[col];
                }
            }
    }
}

// ---------------------------------------------------------------------------
// A[m,h,d,e] = sum_s k[m*S+s, h*64+d] * v[m*S+s, h*64+e]   (bf16 in, fp32 out)
// ---------------------------------------------------------------------------
__global__ __launch_bounds__(256) void kv_outer(const u16* __restrict__ kmat,
                                                const u16* __restrict__ vmat,
                                                float* __restrict__ Abuf)
{
    __shared__ float Ks[32][68];
    __shared__ float Vs[32][68];
    const int t  = threadIdx.x;
    const int hh = blockIdx.x;
    const int m  = blockIdx.y;
    const int td = (t >> 4) * 4;
    const int te = (t & 15) * 4;
    const int sl = t >> 3, cq = t & 7;
    float acc[4][4] = {};

    for (int s0 = 0; s0 < S_SEG; s0 += 32) {
        size_t g = (size_t)(m * S_SEG + s0 + sl) * HD + hh * DHEAD + cq * 8;
        bf16x8 k8 = *reinterpret_cast<const bf16x8*>(&kmat[g]);
        bf16x8 v8 = *reinterpret_cast<const bf16x8*>(&vmat[g]);
#pragma unroll
        for (int j = 0; j < 8; ++j) {
            Ks[sl][cq * 8 + j] = (float)k8[j];
            Vs[sl][cq * 8 + j] = (float)v8[j];
        }
        __syncthreads();
#pragma unroll
        for (int s = 0; s < 32; ++s) {
            float4 a4 = *reinterpret_cast<const float4*>(&Ks[s][td]);
            float4 b4 = *reinterpret_cast<const float4*>(&Vs[s][te]);
            float av[4] = {a4.x, a4.y, a4.z, a4.w};
            float bv[4] = {b4.x, b4.y, b4.z, b4.w};
#pragma unroll
            for (int i = 0; i < 4; ++i)
#pragma unroll
                for (int j = 0; j < 4; ++j)
                    acc[i][j] = fmaf(av[i], bv[j], acc[i][j]);
        }
        __syncthreads();
    }

#pragma unroll
    for (int i = 0; i < 4; ++i) {
        size_t base = ((size_t)(m * NHEAD + hh) * DHEAD + td + i) * DHEAD + te;
        *reinterpret_cast<float4*>(&Abuf[base]) = make_float4(acc[i][0], acc[i][1], acc[i][2], acc[i][3]);
    }
}

// ---------------------------------------------------------------------------
// r_m = A_m + decay*r_{m-1} ;  Bc_m = scale*A_m + gamma^{m+1} * r_m  (fp32)
// ---------------------------------------------------------------------------
__global__ __launch_bounds__(256) void scan_kernel(const float* __restrict__ Abuf,
                                                   float* __restrict__ Bc)
{
    const int tid = blockIdx.x * 256 + threadIdx.x;   // 0..32767
    const float decay = powf(GAMMA_F, (float)S_SEG);
    float r = 0.0f;
    float g = 1.0f;
    for (int m = 0; m < M_SEG; ++m) {
        float a = Abuf[(size_t)m * 32768 + tid];
        r = fmaf(decay, r, a);
        g *= GAMMA_F;
        Bc[(size_t)m * 32768 + tid] = fmaf(g, r, SCALE_F * a);
    }
}

// ---------------------------------------------------------------------------
// h[m,s,h*64+e] = relu( sum_d q[m,s,h*64+d] * Bc[m,h,d,e] )  via MFMA
// ---------------------------------------------------------------------------
__global__ __launch_bounds__(256) void h_mfma(const u16* __restrict__ q,
                                              const float* __restrict__ Bc,
                                              u16* __restrict__ hbuf)
{
    __shared__ __align__(16) u16 BT[64 * 72];    // Bc^T [e][d], pad 72
    const int t    = threadIdx.x;
    const int lane = t & 63;
    const int w    = t >> 6;
    const int m    = blockIdx.y;
    const int sBase = blockIdx.x * 256 + w * 64;
    const int frow = lane & 15;
    const int fkc  = lane >> 4;

    for (int hh = 0; hh < NHEAD; ++hh) {
#pragma unroll
        for (int i = 0; i < 4; ++i) {
            int idx = t + i * 256;               // 1024 float4s
            int d = idx >> 4, e4 = idx & 15;
            float4 v = *reinterpret_cast<const float4*>(
                &Bc[((size_t)(m * NHEAD + hh) * DHEAD + d) * DHEAD + e4 * 4]);
            BT[(e4 * 4 + 0) * 72 + d] = f2bf(v.x);
            BT[(e4 * 4 + 1) * 72 + d] = f2bf(v.y);
            BT[(e4 * 4 + 2) * 72 + d] = f2bf(v.z);
            BT[(e4 * 4 + 3) * 72 + d] = f2bf(v.w);
        }
        __syncthreads();

        f32x4 acc[4][4];
#pragma unroll
        for (int i = 0; i < 4; ++i)
#pragma unroll
            for (int j = 0; j < 4; ++j)
                acc[i][j] = (f32x4){0.f, 0.f, 0.f, 0.f};

#pragma unroll
        for (int ks = 0; ks < 2; ++ks) {
            bf16x8 af[4], bfr[4];
#pragma unroll
            for (int mm = 0; mm < 4; ++mm) {
                const int grow = m * S_SEG + sBase + mm * 16 + frow;
                af[mm] = *reinterpret_cast<const bf16x8*>(
                    &q[(size_t)grow * HD + hh * DHEAD + ks * 32 + fkc * 8]);
                const int e = mm * 16 + frow;
                bfr[mm] = *reinterpret_cast<const bf16x8*>(&BT[e * 72 + ks * 32 + fkc * 8]);
            }
#pragma unroll
            for (int mm = 0; mm < 4; ++mm)
#pragma unroll
                for (int nn = 0; nn < 4; ++nn)
                    acc[mm][nn] = __builtin_amdgcn_mfma_f32_16x16x32_bf16(af[mm], bfr[nn], acc[mm][nn], 0, 0, 0);
        }

        const int orow = (lane >> 4) * 4;
#pragma unroll
        for (int mm = 0; mm < 4; ++mm)
#pragma unroll
            for (int nn = 0; nn < 4; ++nn) {
                const int col  = hh * DHEAD + nn * 16 + frow;
                const int row0 = m * S_SEG + sBase + mm * 16 + orow;
#pragma unroll
                for (int r = 0; r < 4; ++r)
                    hbuf[(size_t)(row0 + r) * HD + col] = f2bf(fmaxf(acc[mm][nn][r], 0.f));
            }
        __syncthreads();
    }
}

// ---------------------------------------------------------------------------
// GroupNorm over (S, 64) per (m, group), in place on d_out rows 1..N
// ---------------------------------------------------------------------------
__global__ __launch_bounds__(256) void groupnorm_kernel(float* __restrict__ out,
                                                        const float* __restrict__ gn_w,
                                                        const float* __restrict__ gn_b)
{
    const int g = blockIdx.x;
    const int m = blockIdx.y;
    const int t = threadIdx.x;
    float* base = out + (size_t)(1 + m * S_SEG) * HD + g * DHEAD;

    float sum = 0.0f, sq = 0.0f;
    for (int idx = t; idx < 8192; idx += 256) {
        int s = idx >> 4;
        int cq = idx & 15;
        float4 v = *reinterpret_cast<const float4*>(&base[(size_t)s * HD + cq * 4]);
        sum += v.x + v.y + v.z + v.w;
        sq  += v.x * v.x + v.y * v.y + v.z * v.z + v.w * v.w;
    }
    __shared__ float rs[256], rq[256];
    rs[t] = sum; rq[t] = sq;
    __syncthreads();
    for (int off = 128; off > 0; off >>= 1) {
        if (t < off) { rs[t] += rs[t + off]; rq[t] += rq[t + off]; }
        __syncthreads();
    }
    __shared__ float smean, sinv;
    if (t == 0) {
        float mean = rs[0] * (1.0f / 32768.0f);
        float var  = rq[0] * (1.0f / 32768.0f) - mean * mean;
        smean = mean;
        sinv  = rsqrtf(var + 1e-5f);
    }
    __syncthreads();
    const float mean = smean, inv = sinv;

    for (int idx = t; idx < 8192; idx += 256) {
        int s = idx >> 4;
        int cq = idx & 15;
        float4 v = *reinterpret_cast<const float4*>(&base[(size_t)s * HD + cq * 4]);
        float4 w4 = *reinterpret_cast<const float4*>(&gn_w[g * DHEAD + cq * 4]);
        float4 b4 = *reinterpret_cast<const float4*>(&gn_b[g * DHEAD + cq * 4]);
        v.x = (v.x - mean) * inv * w4.x + b4.x;
        v.y = (v.y - mean) * inv * w4.y + b4.y;
        v.z = (v.z - mean) * inv * w4.z + b4.z;
        v.w = (v.w - mean) * inv * w4.w + b4.w;
        *reinterpret_cast<float4*>(&base[(size_t)s * HD + cq * 4]) = v;
    }
}

__global__ void zero_row(float* __restrict__ out)
{
    int i = blockIdx.x * 256 + threadIdx.x;
    if (i < HD) out[i] = 0.0f;
}

// ---------------------------------------------------------------------------
extern "C" void kernel_launch(void* const* d_in, const int* in_sizes, int n_in,
                              void* d_out, int out_size, void* d_ws, size_t ws_size,
                              hipStream_t stream)
{
    const float* msg = (const float*)d_in[0];
    const float* Wq  = (const float*)d_in[1];
    const float* Wk  = (const float*)d_in[2];
    const float* Wv  = (const float*)d_in[3];
    const float* Wo  = (const float*)d_in[4];
    const float* bo  = (const float*)d_in[5];
    const float* gnw = (const float*)d_in[6];
    const float* gnb = (const float*)d_in[7];
    float* out = (float*)d_out;

    // d_out scratch (all consumed before the EPI GEMM rewrites d_out):
    //   msgb bf16 (67.1 MB) | Abuf fp32 (16.8 MB) | Bc fp32 (16.8 MB)
    u16*   msgb = (u16*)out;
    float* Abuf = out + 16777216;
    float* Bc   = out + 16777216 + 4194304;

    // d_ws: Wb (2 MB) + q/k/v bf16 (67.1 MB each) = 203.4 MB; h reuses k.
    u16* Wb = (u16*)d_ws;
    u16* qb = Wb + 4 * 262144;
    u16* kb = qb + (size_t)NROWS * HD;
    u16* vb = kb + (size_t)NROWS * HD;
    u16* hb = kb;   // k consumed by kv_outer before h_mfma writes

    convert_bf16<<<128,   256, 0, stream>>>(Wq, Wb + 0 * 262144, 32768);
    convert_bf16<<<128,   256, 0, stream>>>(Wk, Wb + 1 * 262144, 32768);
    convert_bf16<<<128,   256, 0, stream>>>(Wv, Wb + 2 * 262144, 32768);
    convert_bf16<<<128,   256, 0, stream>>>(Wo, Wb + 3 * 262144, 32768);
    convert_bf16<<<16384, 256, 0, stream>>>(msg, msgb, 4194304);

    gemm_bf16<0><<<2048, 256, 0, stream>>>(msgb, Wb + 0 * 262144, qb, nullptr, nullptr);
    gemm_bf16<0><<<2048, 256, 0, stream>>>(msgb, Wb + 1 * 262144, kb, nullptr, nullptr);
    gemm_bf16<0><<<2048, 256, 0, stream>>>(msgb, Wb + 2 * 262144, vb, nullptr, nullptr);

    kv_outer<<<dim3(NHEAD, M_SEG), 256, 0, stream>>>(kb, vb, Abuf);
    scan_kernel<<<128, 256, 0, stream>>>(Abuf, Bc);
    h_mfma<<<dim3(2, M_SEG), 256, 0, stream>>>(qb, Bc, hb);

    gemm_bf16<1><<<2048, 256, 0, stream>>>(hb, Wb + 3 * 262144, out, msg, bo);
    zero_row<<<2, 256, 0, stream>>>(out);
    groupnorm_kernel<<<dim3(8, M_SEG), 256, 0, stream>>>(out, gnw, gnb);
}

// Round 3
// 475.556 us; speedup vs baseline: 4.4354x; 1.0147x over previous
//
#include <hip/hip_runtime.h>
#include <math.h>

// Problem constants (fixed by setup_inputs)
#define M_SEG 128
#define S_SEG 512
#define HD 512
#define NHEAD 8
#define DHEAD 64
#define NROWS (M_SEG * S_SEG)   // 65536
#define QKVLD 1536              // fused qkv row stride
#define GAMMA_F 0.96875f
#define SCALE_F 0.125f          // d^-0.5

typedef unsigned short u16;
typedef float f32x4 __attribute__((ext_vector_type(4)));
typedef __bf16 bf16x8 __attribute__((ext_vector_type(8)));
typedef unsigned short ushort8 __attribute__((ext_vector_type(8)));

__device__ __forceinline__ u16 f2bf(float f) {
    union { float f; unsigned u; } x; x.f = f;
    unsigned r = x.u + 0x7FFFu + ((x.u >> 16) & 1u);   // RNE
    return (u16)(r >> 16);
}

// async global->LDS, 16B per lane; LDS dest = wave-uniform base + lane*16
__device__ __forceinline__ void gload16(const u16* g, u16* l) {
    __builtin_amdgcn_global_load_lds(
        (const __attribute__((address_space(1))) void*)g,
        (__attribute__((address_space(3))) void*)l, 16, 0, 0);
}

// ---------------------------------------------------------------------------
// fp32 -> bf16, 8 elems/thread
// ---------------------------------------------------------------------------
__global__ __launch_bounds__(256) void convert_bf16(const float* __restrict__ in,
                                                    u16* __restrict__ outp, int n8)
{
    int idx = blockIdx.x * 256 + threadIdx.x;
    if (idx >= n8) return;
    const float4 a = *reinterpret_cast<const float4*>(&in[(size_t)idx * 8]);
    const float4 b = *reinterpret_cast<const float4*>(&in[(size_t)idx * 8 + 4]);
    ushort8 o;
    o[0] = f2bf(a.x); o[1] = f2bf(a.y); o[2] = f2bf(a.z); o[3] = f2bf(a.w);
    o[4] = f2bf(b.x); o[5] = f2bf(b.y); o[6] = f2bf(b.z); o[7] = f2bf(b.w);
    *reinterpret_cast<ushort8*>(&outp[(size_t)idx * 8]) = o;
}

// 4 weights in one launch (blockIdx.y selects), each 512x512
__global__ __launch_bounds__(256) void convert_weights(const float* __restrict__ w0,
                                                       const float* __restrict__ w1,
                                                       const float* __restrict__ w2,
                                                       const float* __restrict__ w3,
                                                       u16* __restrict__ outp)
{
    const int which = blockIdx.y;
    const float* src = which == 0 ? w0 : which == 1 ? w1 : which == 2 ? w2 : w3;
    u16* dst = outp + (size_t)which * 262144;
    int idx = blockIdx.x * 256 + threadIdx.x;        // 32768 per weight
    const float4 a = *reinterpret_cast<const float4*>(&src[(size_t)idx * 8]);
    const float4 b = *reinterpret_cast<const float4*>(&src[(size_t)idx * 8 + 4]);
    ushort8 o;
    o[0] = f2bf(a.x); o[1] = f2bf(a.y); o[2] = f2bf(a.z); o[3] = f2bf(a.w);
    o[4] = f2bf(b.x); o[5] = f2bf(b.y); o[6] = f2bf(b.z); o[7] = f2bf(b.w);
    *reinterpret_cast<ushort8*>(&dst[(size_t)idx * 8]) = o;
}

// ---------------------------------------------------------------------------
// 256x256 tile bf16 MFMA GEMM (NT): C[n,i] = sum_j A[n,j]*B[i,j]
// 8 waves (2Mx4N), per-wave 128x64, BK=64, double-buffered global_load_lds.
// EPI==0: C bf16 (ldc param), coalesced via LDS round-trip.
// EPI==1: C = d_out fp32, row n+1 = acc + X[n,:] + bias, LDS-coalesced.
// ---------------------------------------------------------------------------
template<int EPI>
__global__ __launch_bounds__(512, 1) void gemm256(const u16* __restrict__ A, int lda,
                                                  const u16* __restrict__ B,
                                                  void* __restrict__ Cv, int ldc, int ntile,
                                                  const float* __restrict__ X,
                                                  const float* __restrict__ bias)
{
    __shared__ __align__(16) u16 sm[2][2][256 * 64];   // [buf][A|B][row*64+k] : 128 KiB
    const int t    = threadIdx.x;
    const int lane = t & 63;
    const int w    = t >> 6;
    const int wrow = w >> 2;          // 0..1 -> 128 rows
    const int wcol = w & 3;           // 0..3 -> 64 cols

    // XCD-bijective blockIdx swizzle (nwg % 8 == 0 in all uses here)
    const int nwg  = gridDim.x;
    const int cpx  = nwg >> 3;
    const int bid  = blockIdx.x;
    const int sbid = (bid & 7) * cpx + (bid >> 3);
    const int mt = sbid / ntile, nt = sbid % ntile;
    const int rowBase = mt * 256, colBase = nt * 256;

    // staging geometry: 32 chunks of 1024B per matrix, wave w owns chunks w*4..w*4+3
    const int chunkBase = w * 4;
    const int srow = lane >> 3;       // row within 8-row chunk
    const int scol = lane & 7;        // 16B unit within 128B row

    f32x4 acc[8][4];
#pragma unroll
    for (int i = 0; i < 8; ++i)
#pragma unroll
        for (int j = 0; j < 4; ++j)
            acc[i][j] = (f32x4){0.f, 0.f, 0.f, 0.f};

    // prologue: stage K-tile 0 into buf 0
#pragma unroll
    for (int i = 0; i < 4; ++i) {
        const int ch = chunkBase + i;
        const int ar = ch * 8 + srow;
        gload16(&A[(size_t)(rowBase + ar) * lda + scol * 8], &sm[0][0][ch * 512]);
        gload16(&B[(size_t)(colBase + ar) * HD  + scol * 8], &sm[0][1][ch * 512]);
    }
    __syncthreads();

    const int frow = lane & 15;
    const int fkc  = lane >> 4;

    for (int kt = 0; kt < 8; ++kt) {
        const int cur = kt & 1;
        if (kt < 7) {
            const int k0 = (kt + 1) * 64;
#pragma unroll
            for (int i = 0; i < 4; ++i) {
                const int ch = chunkBase + i;
                const int ar = ch * 8 + srow;
                gload16(&A[(size_t)(rowBase + ar) * lda + k0 + scol * 8], &sm[cur ^ 1][0][ch * 512]);
                gload16(&B[(size_t)(colBase + ar) * HD  + k0 + scol * 8], &sm[cur ^ 1][1][ch * 512]);
            }
        }
        const u16* As = sm[cur][0];
        const u16* Bs = sm[cur][1];
#pragma unroll
        for (int ks = 0; ks < 2; ++ks) {
            bf16x8 af[8], bfr[4];
#pragma unroll
            for (int mm = 0; mm < 8; ++mm)
                af[mm] = *reinterpret_cast<const bf16x8*>(
                    &As[(wrow * 128 + mm * 16 + frow) * 64 + ks * 32 + fkc * 8]);
#pragma unroll
            for (int nn = 0; nn < 4; ++nn)
                bfr[nn] = *reinterpret_cast<const bf16x8*>(
                    &Bs[(wcol * 64 + nn * 16 + frow) * 64 + ks * 32 + fkc * 8]);
#pragma unroll
            for (int mm = 0; mm < 8; ++mm)
#pragma unroll
                for (int nn = 0; nn < 4; ++nn)
                    acc[mm][nn] = __builtin_amdgcn_mfma_f32_16x16x32_bf16(af[mm], bfr[nn], acc[mm][nn], 0, 0, 0);
        }
        __syncthreads();   // drains vmcnt(0): next tile staged; readers done with cur
    }

    const int orow = (lane >> 4) * 4;   // C/D: row=(lane>>4)*4+r, col=lane&15
    if (EPI == 0) {
        // acc -> LDS (256x256 u16 = exactly 128 KiB) -> coalesced ushort8 stores
        u16* ldsC = (u16*)sm;
#pragma unroll
        for (int mm = 0; mm < 8; ++mm)
#pragma unroll
            for (int nn = 0; nn < 4; ++nn) {
                const int row0 = wrow * 128 + mm * 16 + orow;
                const int col  = wcol * 64 + nn * 16 + frow;
#pragma unroll
                for (int r = 0; r < 4; ++r)
                    ldsC[(row0 + r) * 256 + col] = f2bf(acc[mm][nn][r]);
            }
        __syncthreads();
        u16* C = (u16*)Cv;
#pragma unroll
        for (int p = 0; p < 16; ++p) {
            const int lin = p * 512 + t;          // 8192 x 16B chunks
            const int row = lin >> 5, c8 = lin & 31;
            *reinterpret_cast<ushort8*>(&C[(size_t)(rowBase + row) * ldc + colBase + c8 * 8]) =
                *reinterpret_cast<const ushort8*>(&ldsC[row * 256 + c8 * 8]);
        }
    } else {
        // two half-passes of fp32 through LDS (128x256 f32 = 128 KiB)
        float* ldsF = (float*)sm;
        float* C = (float*)Cv;
#pragma unroll
        for (int half = 0; half < 2; ++half) {
            if (wrow == half) {
#pragma unroll
                for (int mm = 0; mm < 8; ++mm)
#pragma unroll
                    for (int nn = 0; nn < 4; ++nn) {
                        const int row0 = mm * 16 + orow;          // 0..127 local
                        const int col  = wcol * 64 + nn * 16 + frow;
#pragma unroll
                        for (int r = 0; r < 4; ++r)
                            ldsF[(row0 + r) * 256 + col] = acc[mm][nn][r];
                    }
            }
            __syncthreads();
#pragma unroll
            for (int p = 0; p < 16; ++p) {
                const int lin = p * 512 + t;      // 8192 float4s
                const int row = lin >> 6, c4 = lin & 63;
                const int grow = rowBase + half * 128 + row;
                float4 a = *reinterpret_cast<const float4*>(&ldsF[row * 256 + c4 * 4]);
                float4 x = *reinterpret_cast<const float4*>(&X[(size_t)grow * HD + colBase + c4 * 4]);
                float4 b = *reinterpret_cast<const float4*>(&bias[colBase + c4 * 4]);
                float4 o = make_float4(a.x + x.x + b.x, a.y + x.y + b.y,
                                       a.z + x.z + b.z, a.w + x.w + b.w);
                *reinterpret_cast<float4*>(&C[(size_t)(grow + 1) * HD + colBase + c4 * 4]) = o;
            }
            __syncthreads();
        }
    }
}

// ---------------------------------------------------------------------------
// A[m,h,d,e] = sum_s k[m,s,d] * v[m,s,e] from fused qkv (stride 1536)
// ---------------------------------------------------------------------------
__global__ __launch_bounds__(256) void kv_outer(const u16* __restrict__ qkv,
                                                float* __restrict__ Abuf)
{
    __shared__ float Ks[32][68];
    __shared__ float Vs[32][68];
    const int t  = threadIdx.x;
    const int hh = blockIdx.x;
    const int m  = blockIdx.y;
    const int td = (t >> 4) * 4;
    const int te = (t & 15) * 4;
    const int sl = t >> 3, cq = t & 7;
    float acc[4][4] = {};

    for (int s0 = 0; s0 < S_SEG; s0 += 32) {
        size_t g = (size_t)(m * S_SEG + s0 + sl) * QKVLD + hh * DHEAD + cq * 8;
        bf16x8 k8 = *reinterpret_cast<const bf16x8*>(&qkv[g + 512]);    // k slot
        bf16x8 v8 = *reinterpret_cast<const bf16x8*>(&qkv[g + 1024]);   // v slot
#pragma unroll
        for (int j = 0; j < 8; ++j) {
            Ks[sl][cq * 8 + j] = (float)k8[j];
            Vs[sl][cq * 8 + j] = (float)v8[j];
        }
        __syncthreads();
#pragma unroll
        for (int s = 0; s < 32; ++s) {
            float4 a4 = *reinterpret_cast<const float4*>(&Ks[s][td]);
            float4 b4 = *reinterpret_cast<const float4*>(&Vs[s][te]);
            float av[4] = {a4.x, a4.y, a4.z, a4.w};
            float bv[4] = {b4.x, b4.y, b4.z, b4.w};
#pragma unroll
            for (int i = 0; i < 4; ++i)
#pragma unroll
                for (int j = 0; j < 4; ++j)
                    acc[i][j] = fmaf(av[i], bv[j], acc[i][j]);
        }
        __syncthreads();
    }

#pragma unroll
    for (int i = 0; i < 4; ++i) {
        size_t base = ((size_t)(m * NHEAD + hh) * DHEAD + td + i) * DHEAD + te;
        *reinterpret_cast<float4*>(&Abuf[base]) = make_float4(acc[i][0], acc[i][1], acc[i][2], acc[i][3]);
    }
}

// ---------------------------------------------------------------------------
// r_m = A_m + decay*r_{m-1} ;  Bc_m = scale*A_m + gamma^{m+1} * r_m  (fp32)
// ---------------------------------------------------------------------------
__global__ __launch_bounds__(256) void scan_kernel(const float* __restrict__ Abuf,
                                                   float* __restrict__ Bc)
{
    const int tid = blockIdx.x * 256 + threadIdx.x;   // 0..32767
    const float decay = powf(GAMMA_F, (float)S_SEG);
    float r = 0.0f;
    float g = 1.0f;
    for (int m = 0; m < M_SEG; ++m) {
        float a = Abuf[(size_t)m * 32768 + tid];
        r = fmaf(decay, r, a);
        g *= GAMMA_F;
        Bc[(size_t)m * 32768 + tid] = fmaf(g, r, SCALE_F * a);
    }
}

// ---------------------------------------------------------------------------
// h = relu(q @ Bc) written IN PLACE into qkv's q-slot (rows partitioned by
// wave; head-column read happens before same-column write within each wave).
// ---------------------------------------------------------------------------
__global__ __launch_bounds__(256) void h_mfma(u16* __restrict__ qkv,
                                              const float* __restrict__ Bc)
{
    __shared__ __align__(16) u16 BT[64 * 72];    // Bc^T [e][d], pad 72
    const int t    = threadIdx.x;
    const int lane = t & 63;
    const int w    = t >> 6;
    const int m    = blockIdx.y;
    const int sBase = blockIdx.x * 256 + w * 64;
    const int frow = lane & 15;
    const int fkc  = lane >> 4;

    for (int hh = 0; hh < NHEAD; ++hh) {
#pragma unroll
        for (int i = 0; i < 4; ++i) {
            int idx = t + i * 256;               // 1024 float4s
            int d = idx >> 4, e4 = idx & 15;
            float4 v = *reinterpret_cast<const float4*>(
                &Bc[((size_t)(m * NHEAD + hh) * DHEAD + d) * DHEAD + e4 * 4]);
            BT[(e4 * 4 + 0) * 72 + d] = f2bf(v.x);
            BT[(e4 * 4 + 1) * 72 + d] = f2bf(v.y);
            BT[(e4 * 4 + 2) * 72 + d] = f2bf(v.z);
            BT[(e4 * 4 + 3) * 72 + d] = f2bf(v.w);
        }
        __syncthreads();

        f32x4 acc[4][4];
#pragma unroll
        for (int i = 0; i < 4; ++i)
#pragma unroll
            for (int j = 0; j < 4; ++j)
                acc[i][j] = (f32x4){0.f, 0.f, 0.f, 0.f};

#pragma unroll
        for (int ks = 0; ks < 2; ++ks) {
            bf16x8 af[4], bfr[4];
#pragma unroll
            for (int mm = 0; mm < 4; ++mm) {
                const int grow = m * S_SEG + sBase + mm * 16 + frow;
                af[mm] = *reinterpret_cast<const bf16x8*>(
                    &qkv[(size_t)grow * QKVLD + hh * DHEAD + ks * 32 + fkc * 8]);
                const int e = mm * 16 + frow;
                bfr[mm] = *reinterpret_cast<const bf16x8*>(&BT[e * 72 + ks * 32 + fkc * 8]);
            }
#pragma unroll
            for (int mm = 0; mm < 4; ++mm)
#pragma unroll
                for (int nn = 0; nn < 4; ++nn)
                    acc[mm][nn] = __builtin_amdgcn_mfma_f32_16x16x32_bf16(af[mm], bfr[nn], acc[mm][nn], 0, 0, 0);
        }

        const int orow = (lane >> 4) * 4;
#pragma unroll
        for (int mm = 0; mm < 4; ++mm)
#pragma unroll
            for (int nn = 0; nn < 4; ++nn) {
                const int col  = hh * DHEAD + nn * 16 + frow;
                const int row0 = m * S_SEG + sBase + mm * 16 + orow;
#pragma unroll
                for (int r = 0; r < 4; ++r)
                    qkv[(size_t)(row0 + r) * QKVLD + col] = f2bf(fmaxf(acc[mm][nn][r], 0.f));
            }
        __syncthreads();
    }
}

// ---------------------------------------------------------------------------
// GroupNorm over (S, 64) per (m, group), in place on d_out rows 1..N
// ---------------------------------------------------------------------------
__global__ __launch_bounds__(256) void groupnorm_kernel(float* __restrict__ out,
                                                        const float* __restrict__ gn_w,
                                                        const float* __restrict__ gn_b)
{
    const int g = blockIdx.x;
    const int m = blockIdx.y;
    const int t = threadIdx.x;
    float* base = out + (size_t)(1 + m * S_SEG) * HD + g * DHEAD;

    float sum = 0.0f, sq = 0.0f;
    for (int idx = t; idx < 8192; idx += 256) {
        int s = idx >> 4;
        int cq = idx & 15;
        float4 v = *reinterpret_cast<const float4*>(&base[(size_t)s * HD + cq * 4]);
        sum += v.x + v.y + v.z + v.w;
        sq  += v.x * v.x + v.y * v.y + v.z * v.z + v.w * v.w;
    }
    __shared__ float rs[256], rq[256];
    rs[t] = sum; rq[t] = sq;
    __syncthreads();
    for (int off = 128; off > 0; off >>= 1) {
        if (t < off) { rs[t] += rs[t + off]; rq[t] += rq[t + off]; }
        __syncthreads();
    }
    __shared__ float smean, sinv;
    if (t == 0) {
        float mean = rs[0] * (1.0f / 32768.0f);
        float var  = rq[0] * (1.0f / 32768.0f) - mean * mean;
        smean = mean;
        sinv  = rsqrtf(var + 1e-5f);
    }
    __syncthreads();
    const float mean = smean, inv = sinv;

    for (int idx = t; idx < 8192; idx += 256) {
        int s = idx >> 4;
        int cq = idx & 15;
        float4 v = *reinterpret_cast<const float4*>(&base[(size_t)s * HD + cq * 4]);
        float4 w4 = *reinterpret_cast<const float4*>(&gn_w[g * DHEAD + cq * 4]);
        float4 b4 = *reinterpret_cast<const float4*>(&gn_b[g * DHEAD + cq * 4]);
        v.x = (v.x - mean) * inv * w4.x + b4.x;
        v.y = (v.y - mean) * inv * w4.y + b4.y;
        v.z = (v.z - mean) * inv * w4.z + b4.z;
        v.w = (v.w - mean) * inv * w4.w + b4.w;
        *reinterpret_cast<float4*>(&base[(size_t)s * HD + cq * 4]) = v;
    }
}

__global__ void zero_row(float* __restrict__ out)
{
    int i = blockIdx.x * 256 + threadIdx.x;
    if (i < HD) out[i] = 0.0f;
}

// ---------------------------------------------------------------------------
extern "C" void kernel_launch(void* const* d_in, const int* in_sizes, int n_in,
                              void* d_out, int out_size, void* d_ws, size_t ws_size,
                              hipStream_t stream)
{
    const float* msg = (const float*)d_in[0];
    const float* Wq  = (const float*)d_in[1];
    const float* Wk  = (const float*)d_in[2];
    const float* Wv  = (const float*)d_in[3];
    const float* Wo  = (const float*)d_in[4];
    const float* bo  = (const float*)d_in[5];
    const float* gnw = (const float*)d_in[6];
    const float* gnb = (const float*)d_in[7];
    float* out = (float*)d_out;

    // d_out scratch (consumed before the EPI GEMM rewrites d_out):
    //   msgb bf16 (67.1 MB) | Abuf fp32 (16.8 MB) | Bc fp32 (16.8 MB)
    u16*   msgb = (u16*)out;
    float* Abuf = out + 16777216;
    float* Bc   = out + 16777216 + 4194304;

    // d_ws: Wb 2 MB (Wq|Wk|Wv|Wo bf16) + qkv 201.3 MB (65536 x 1536).
    // h_mfma overwrites qkv's q-slot with h in place.
    u16* Wb  = (u16*)d_ws;
    u16* qkv = Wb + 4 * 262144;

    convert_weights<<<dim3(128, 4), 256, 0, stream>>>(Wq, Wk, Wv, Wo, Wb);
    convert_bf16<<<16384, 256, 0, stream>>>(msg, msgb, 4194304);

    // fused QKV GEMM: A=msgb (65536x512), B=[Wq;Wk;Wv] (1536x512) -> qkv
    gemm256<0><<<1536, 512, 0, stream>>>(msgb, HD, Wb, qkv, QKVLD, 6, nullptr, nullptr);

    kv_outer<<<dim3(NHEAD, M_SEG), 256, 0, stream>>>(qkv, Abuf);
    scan_kernel<<<128, 256, 0, stream>>>(Abuf, Bc);
    h_mfma<<<dim3(2, M_SEG), 256, 0, stream>>>(qkv, Bc);

    // output GEMM: A=h (qkv q-slot, lda=1536), B=Wo -> d_out (+msg+bias, +1 row)
    gemm256<1><<<512, 512, 0, stream>>>(qkv, QKVLD, Wb + 3 * 262144, out, HD, 2, msg, bo);

    zero_row<<<2, 256, 0, stream>>>(out);
    groupnorm_kernel<<<dim3(8, M_SEG), 256, 0, stream>>>(out, gnw, gnb);
}

// Round 4
// 397.928 us; speedup vs baseline: 5.3006x; 1.1951x over previous
//
#include <hip/hip_runtime.h>
#include <math.h>

// Problem constants (fixed by setup_inputs)
#define M_SEG 128
#define S_SEG 512
#define HD 512
#define NHEAD 8
#define DHEAD 64
#define NROWS (M_SEG * S_SEG)   // 65536
#define QKVLD 1536              // fused qkv row stride
#define GAMMA_F 0.96875f
#define SCALE_F 0.125f          // d^-0.5

typedef unsigned short u16;
typedef float f32x4 __attribute__((ext_vector_type(4)));
typedef __bf16 bf16x8 __attribute__((ext_vector_type(8)));
typedef unsigned short ushort8 __attribute__((ext_vector_type(8)));
typedef unsigned short ushort4v __attribute__((ext_vector_type(4)));

__device__ __forceinline__ u16 f2bf(float f) {
    union { float f; unsigned u; } x; x.f = f;
    unsigned r = x.u + 0x7FFFu + ((x.u >> 16) & 1u);   // RNE
    return (u16)(r >> 16);
}
__device__ __forceinline__ float bf2f(u16 v) {
    union { unsigned u; float f; } x; x.u = ((unsigned)v) << 16;
    return x.f;
}

// async global->LDS, 16B per lane; LDS dest = wave-uniform base + lane*16
__device__ __forceinline__ void gload16(const u16* g, u16* l) {
    __builtin_amdgcn_global_load_lds(
        (const __attribute__((address_space(1))) void*)g,
        (__attribute__((address_space(3))) void*)l, 16, 0, 0);
}

// ---------------------------------------------------------------------------
// fp32 -> bf16, 8 elems/thread
// ---------------------------------------------------------------------------
__global__ __launch_bounds__(256) void convert_bf16(const float* __restrict__ in,
                                                    u16* __restrict__ outp, int n8)
{
    int idx = blockIdx.x * 256 + threadIdx.x;
    if (idx >= n8) return;
    const float4 a = *reinterpret_cast<const float4*>(&in[(size_t)idx * 8]);
    const float4 b = *reinterpret_cast<const float4*>(&in[(size_t)idx * 8 + 4]);
    ushort8 o;
    o[0] = f2bf(a.x); o[1] = f2bf(a.y); o[2] = f2bf(a.z); o[3] = f2bf(a.w);
    o[4] = f2bf(b.x); o[5] = f2bf(b.y); o[6] = f2bf(b.z); o[7] = f2bf(b.w);
    *reinterpret_cast<ushort8*>(&outp[(size_t)idx * 8]) = o;
}

// 4 weights in one launch (blockIdx.y selects), each 512x512
__global__ __launch_bounds__(256) void convert_weights(const float* __restrict__ w0,
                                                       const float* __restrict__ w1,
                                                       const float* __restrict__ w2,
                                                       const float* __restrict__ w3,
                                                       u16* __restrict__ outp)
{
    const int which = blockIdx.y;
    const float* src = which == 0 ? w0 : which == 1 ? w1 : which == 2 ? w2 : w3;
    u16* dst = outp + (size_t)which * 262144;
    int idx = blockIdx.x * 256 + threadIdx.x;        // 32768 per weight
    const float4 a = *reinterpret_cast<const float4*>(&src[(size_t)idx * 8]);
    const float4 b = *reinterpret_cast<const float4*>(&src[(size_t)idx * 8 + 4]);
    ushort8 o;
    o[0] = f2bf(a.x); o[1] = f2bf(a.y); o[2] = f2bf(a.z); o[3] = f2bf(a.w);
    o[4] = f2bf(b.x); o[5] = f2bf(b.y); o[6] = f2bf(b.z); o[7] = f2bf(b.w);
    *reinterpret_cast<ushort8*>(&dst[(size_t)idx * 8]) = o;
}

// ---------------------------------------------------------------------------
// 256x256-tile bf16 MFMA GEMM (NT): C[n,i] = sum_j A[n,j]*B[i,j], K=512.
// BK=32, 16 K-tiles, 3 LDS buffers (96 KiB), counted vmcnt (never 0 mid-loop):
//   iter kt: issue stage(kt+2 -> buf (kt+2)%3); s_waitcnt vmcnt(8) guarantees
//   tile kt landed (2 tiles x 4 loads/thread may stay in flight); raw barrier;
//   frag reads + 32 MFMA; raw barrier (frees buf kt%3 for restage at kt+1).
// LDS swizzle both-sides (rule 21): gload dest linear, global source column
// pre-swizzled slot^((row>>1)&3), frag read applies same XOR -> 2-way banks.
// 8 waves (2Mx4N), per-wave 128x64.
// EPI==0: C bf16 (ldc), coalesced via LDS half-passes.
// EPI==1: res = acc + X(bf16) + bias -> bf16 at Cv (ldc), LDS quarter-passes.
// ---------------------------------------------------------------------------
template<int EPI>
__global__ __launch_bounds__(512, 1) void gemm256(const u16* __restrict__ A, int lda,
                                                  const u16* __restrict__ B,
                                                  u16* __restrict__ Cv, int ldc, int ntile,
                                                  const u16* __restrict__ Xb,
                                                  const float* __restrict__ bias)
{
    // [buf][mat A|B][half][128 rows * 32 k] u16 = 3*2*2*4096 = 96 KiB
    __shared__ __align__(16) u16 sm[49152];
    const int t    = threadIdx.x;
    const int lane = t & 63;
    const int w    = t >> 6;
    const int wrow = w >> 2;          // 0..1 -> A-half
    const int wcol = w & 3;           // 0..3

    // XCD-bijective blockIdx swizzle (nwg % 8 == 0 in all uses here)
    const int nwg  = gridDim.x;
    const int cpx  = nwg >> 3;
    const int bid  = blockIdx.x;
    const int sbid = (bid & 7) * cpx + (bid >> 3);
    const int mt = sbid / ntile, nt = sbid % ntile;
    const int rowBase = mt * 256, colBase = nt * 256;

    // staging geometry: thread t handles (row = t>>2, slot = t&3) of each half
    const int srow = t >> 2;                          // 0..127
    const int scol = ((t & 3) ^ ((srow >> 1) & 3)) * 8;  // swizzled source col

    const size_t gA0 = (size_t)(rowBase +       srow) * lda + scol;
    const size_t gA1 = (size_t)(rowBase + 128 + srow) * lda + scol;
    const size_t gB0 = (size_t)(colBase +       srow) * HD  + scol;
    const size_t gB1 = (size_t)(colBase + 128 + srow) * HD  + scol;

    f32x4 acc[8][4];
#pragma unroll
    for (int i = 0; i < 8; ++i)
#pragma unroll
        for (int j = 0; j < 4; ++j)
            acc[i][j] = (f32x4){0.f, 0.f, 0.f, 0.f};

#define STAGE(kt, buf)                                                        \
    do {                                                                      \
        const int k0_ = (kt) * 32;                                            \
        u16* b_ = &sm[(buf) * 16384];                                         \
        gload16(&A[gA0 + k0_], &b_[        t * 8]);                           \
        gload16(&A[gA1 + k0_], &b_[4096  + t * 8]);                           \
        gload16(&B[gB0 + k0_], &b_[8192  + t * 8]);                           \
        gload16(&B[gB1 + k0_], &b_[12288 + t * 8]);                           \
    } while (0)

    STAGE(0, 0);
    STAGE(1, 1);

    const int frow = lane & 15;
    const int fkc  = lane >> 4;
    const int brow0 = (wcol & 1) * 64;

    for (int kt = 0; kt < 16; ++kt) {
        const int buf = kt % 3;
        if (kt + 2 < 16) STAGE(kt + 2, (kt + 2) % 3);
        if (kt < 14)       asm volatile("s_waitcnt vmcnt(8)" ::: "memory");
        else if (kt == 14) asm volatile("s_waitcnt vmcnt(4)" ::: "memory");
        else               asm volatile("s_waitcnt vmcnt(0)" ::: "memory");
        __builtin_amdgcn_s_barrier();
        __builtin_amdgcn_sched_barrier(0);

        const u16* Ah = &sm[buf * 16384 + wrow * 4096];
        const u16* Bh = &sm[buf * 16384 + 8192 + (wcol >> 1) * 4096];
        bf16x8 af[8], bfv[4];
#pragma unroll
        for (int mm = 0; mm < 8; ++mm) {
            const int r = mm * 16 + frow;
            af[mm] = *reinterpret_cast<const bf16x8*>(
                &Ah[r * 32 + ((fkc ^ ((r >> 1) & 3)) << 3)]);
        }
#pragma unroll
        for (int nn = 0; nn < 4; ++nn) {
            const int r = brow0 + nn * 16 + frow;
            bfv[nn] = *reinterpret_cast<const bf16x8*>(
                &Bh[r * 32 + ((fkc ^ ((r >> 1) & 3)) << 3)]);
        }
#pragma unroll
        for (int mm = 0; mm < 8; ++mm)
#pragma unroll
            for (int nn = 0; nn < 4; ++nn)
                acc[mm][nn] = __builtin_amdgcn_mfma_f32_16x16x32_bf16(af[mm], bfv[nn], acc[mm][nn], 0, 0, 0);

        __builtin_amdgcn_s_barrier();   // all waves done reading buf kt%3
    }
#undef STAGE

    const int orow = (lane >> 4) * 4;   // C/D: row=(lane>>4)*4+r, col=lane&15
    if (EPI == 0) {
        // two half-passes: 128x256 u16 = 64 KiB in LDS, coalesced ushort8 out
        u16* ldsC = sm;
#pragma unroll
        for (int hp = 0; hp < 2; ++hp) {
            __syncthreads();
            if (wrow == hp) {
#pragma unroll
                for (int mm = 0; mm < 8; ++mm)
#pragma unroll
                    for (int nn = 0; nn < 4; ++nn) {
                        const int row0 = mm * 16 + orow;
                        const int col  = wcol * 64 + nn * 16 + frow;
#pragma unroll
                        for (int r = 0; r < 4; ++r)
                            ldsC[(row0 + r) * 256 + col] = f2bf(acc[mm][nn][r]);
                    }
            }
            __syncthreads();
#pragma unroll
            for (int p = 0; p < 8; ++p) {
                const int lin = p * 512 + t;          // 4096 x 16B chunks
                const int row = lin >> 5, c8 = lin & 31;
                *reinterpret_cast<ushort8*>(
                    &Cv[(size_t)(rowBase + hp * 128 + row) * ldc + colBase + c8 * 8]) =
                    *reinterpret_cast<const ushort8*>(&ldsC[row * 256 + c8 * 8]);
            }
        }
    } else {
        // four quarter-passes: 64x256 f32 = 64 KiB; res = acc + X + bias -> bf16
        float* ldsF = (float*)sm;
#pragma unroll
        for (int q = 0; q < 4; ++q) {
            __syncthreads();
            if (wrow == (q >> 1)) {
#pragma unroll
                for (int mm = 0; mm < 4; ++mm) {
                    const int macc = (q & 1) * 4 + mm;
#pragma unroll
                    for (int nn = 0; nn < 4; ++nn) {
                        const int row0 = mm * 16 + orow;
                        const int col  = wcol * 64 + nn * 16 + frow;
#pragma unroll
                        for (int r = 0; r < 4; ++r)
                            ldsF[(row0 + r) * 256 + col] = acc[macc][nn][r];
                    }
                }
            }
            __syncthreads();
#pragma unroll
            for (int p = 0; p < 8; ++p) {
                const int lin = p * 512 + t;          // 4096 float4 chunks
                const int row = lin >> 6, c4 = lin & 63;
                const int grow = rowBase + q * 64 + row;
                float4 a = *reinterpret_cast<const float4*>(&ldsF[row * 256 + c4 * 4]);
                ushort4v x4 = *reinterpret_cast<const ushort4v*>(
                    &Xb[(size_t)grow * HD + colBase + c4 * 4]);
                float4 b = *reinterpret_cast<const float4*>(&bias[colBase + c4 * 4]);
                ushort4v o;
                o[0] = f2bf(a.x + bf2f(x4[0]) + b.x);
                o[1] = f2bf(a.y + bf2f(x4[1]) + b.y);
                o[2] = f2bf(a.z + bf2f(x4[2]) + b.z);
                o[3] = f2bf(a.w + bf2f(x4[3]) + b.w);
                *reinterpret_cast<ushort4v*>(
                    &Cv[(size_t)grow * ldc + colBase + c4 * 4]) = o;
            }
        }
    }
}

// ---------------------------------------------------------------------------
// A[m,h,d,e] = sum_s k[m,s,d] * v[m,s,e] from fused qkv (stride 1536)
// ---------------------------------------------------------------------------
__global__ __launch_bounds__(256) void kv_outer(const u16* __restrict__ qkv,
                                                float* __restrict__ Abuf)
{
    __shared__ float Ks[32][68];
    __shared__ float Vs[32][68];
    const int t  = threadIdx.x;
    const int hh = blockIdx.x;
    const int m  = blockIdx.y;
    const int td = (t >> 4) * 4;
    const int te = (t & 15) * 4;
    const int sl = t >> 3, cq = t & 7;
    float acc[4][4] = {};

    for (int s0 = 0; s0 < S_SEG; s0 += 32) {
        size_t g = (size_t)(m * S_SEG + s0 + sl) * QKVLD + hh * DHEAD + cq * 8;
        bf16x8 k8 = *reinterpret_cast<const bf16x8*>(&qkv[g + 512]);    // k slot
        bf16x8 v8 = *reinterpret_cast<const bf16x8*>(&qkv[g + 1024]);   // v slot
#pragma unroll
        for (int j = 0; j < 8; ++j) {
            Ks[sl][cq * 8 + j] = (float)k8[j];
            Vs[sl][cq * 8 + j] = (float)v8[j];
        }
        __syncthreads();
#pragma unroll
        for (int s = 0; s < 32; ++s) {
            float4 a4 = *reinterpret_cast<const float4*>(&Ks[s][td]);
            float4 b4 = *reinterpret_cast<const float4*>(&Vs[s][te]);
            float av[4] = {a4.x, a4.y, a4.z, a4.w};
            float bv[4] = {b4.x, b4.y, b4.z, b4.w};
#pragma unroll
            for (int i = 0; i < 4; ++i)
#pragma unroll
                for (int j = 0; j < 4; ++j)
                    acc[i][j] = fmaf(av[i], bv[j], acc[i][j]);
        }
        __syncthreads();
    }

#pragma unroll
    for (int i = 0; i < 4; ++i) {
        size_t base = ((size_t)(m * NHEAD + hh) * DHEAD + td + i) * DHEAD + te;
        *reinterpret_cast<float4*>(&Abuf[base]) = make_float4(acc[i][0], acc[i][1], acc[i][2], acc[i][3]);
    }
}

// ---------------------------------------------------------------------------
// r_m = A_m + decay*r_{m-1} ;  Bc_m = scale*A_m + gamma^{m+1} * r_m  (fp32)
// ---------------------------------------------------------------------------
__global__ __launch_bounds__(256) void scan_kernel(const float* __restrict__ Abuf,
                                                   float* __restrict__ Bc)
{
    const int tid = blockIdx.x * 256 + threadIdx.x;   // 0..32767
    const float decay = powf(GAMMA_F, (float)S_SEG);
    float r = 0.0f;
    float g = 1.0f;
    for (int m = 0; m < M_SEG; ++m) {
        float a = Abuf[(size_t)m * 32768 + tid];
        r = fmaf(decay, r, a);
        g *= GAMMA_F;
        Bc[(size_t)m * 32768 + tid] = fmaf(g, r, SCALE_F * a);
    }
}

// ---------------------------------------------------------------------------
// h = relu(q @ Bc) written IN PLACE into qkv's q-slot
// ---------------------------------------------------------------------------
__global__ __launch_bounds__(256) void h_mfma(u16* __restrict__ qkv,
                                              const float* __restrict__ Bc)
{
    __shared__ __align__(16) u16 BT[64 * 72];    // Bc^T [e][d], pad 72
    const int t    = threadIdx.x;
    const int lane = t & 63;
    const int w    = t >> 6;
    const int m    = blockIdx.y;
    const int sBase = blockIdx.x * 256 + w * 64;
    const int frow = lane & 15;
    const int fkc  = lane >> 4;

    for (int hh = 0; hh < NHEAD; ++hh) {
#pragma unroll
        for (int i = 0; i < 4; ++i) {
            int idx = t + i * 256;               // 1024 float4s
            int d = idx >> 4, e4 = idx & 15;
            float4 v = *reinterpret_cast<const float4*>(
                &Bc[((size_t)(m * NHEAD + hh) * DHEAD + d) * DHEAD + e4 * 4]);
            BT[(e4 * 4 + 0) * 72 + d] = f2bf(v.x);
            BT[(e4 * 4 + 1) * 72 + d] = f2bf(v.y);
            BT[(e4 * 4 + 2) * 72 + d] = f2bf(v.z);
            BT[(e4 * 4 + 3) * 72 + d] = f2bf(v.w);
        }
        __syncthreads();

        f32x4 acc[4][4];
#pragma unroll
        for (int i = 0; i < 4; ++i)
#pragma unroll
            for (int j = 0; j < 4; ++j)
                acc[i][j] = (f32x4){0.f, 0.f, 0.f, 0.f};

#pragma unroll
        for (int ks = 0; ks < 2; ++ks) {
            bf16x8 af[4], bfr[4];
#pragma unroll
            for (int mm = 0; mm < 4; ++mm) {
                const int grow = m * S_SEG + sBase + mm * 16 + frow;
                af[mm] = *reinterpret_cast<const bf16x8*>(
                    &qkv[(size_t)grow * QKVLD + hh * DHEAD + ks * 32 + fkc * 8]);
                const int e = mm * 16 + frow;
                bfr[mm] = *reinterpret_cast<const bf16x8*>(&BT[e * 72 + ks * 32 + fkc * 8]);
            }
#pragma unroll
            for (int mm = 0; mm < 4; ++mm)
#pragma unroll
                for (int nn = 0; nn < 4; ++nn)
                    acc[mm][nn] = __builtin_amdgcn_mfma_f32_16x16x32_bf16(af[mm], bfr[nn], acc[mm][nn], 0, 0, 0);
        }

        const int orow = (lane >> 4) * 4;
#pragma unroll
        for (int mm = 0; mm < 4; ++mm)
#pragma unroll
            for (int nn = 0; nn < 4; ++nn) {
                const int col  = hh * DHEAD + nn * 16 + frow;
                const int row0 = m * S_SEG + sBase + mm * 16 + orow;
#pragma unroll
                for (int r = 0; r < 4; ++r)
                    qkv[(size_t)(row0 + r) * QKVLD + col] = f2bf(fmaxf(acc[mm][nn][r], 0.f));
            }
        __syncthreads();
    }
}

// ---------------------------------------------------------------------------
// GroupNorm from bf16 res (qkv k-slot, stride 1536) -> fp32 d_out rows 1..N
// ---------------------------------------------------------------------------
__global__ __launch_bounds__(256) void groupnorm_bf16(const u16* __restrict__ res,
                                                      float* __restrict__ out,
                                                      const float* __restrict__ gn_w,
                                                      const float* __restrict__ gn_b)
{
    const int g = blockIdx.x;
    const int m = blockIdx.y;
    const int t = threadIdx.x;
    const u16* base = res + (size_t)(m * S_SEG) * QKVLD + g * DHEAD;

    float sum = 0.0f, sq = 0.0f;
    for (int idx = t; idx < 4096; idx += 256) {      // 512 rows x 8 ushort8
        int s = idx >> 3, c8 = idx & 7;
        ushort8 v = *reinterpret_cast<const ushort8*>(&base[(size_t)s * QKVLD + c8 * 8]);
#pragma unroll
        for (int j = 0; j < 8; ++j) {
            float f = bf2f(v[j]);
            sum += f; sq += f * f;
        }
    }
    __shared__ float rs[256], rq[256];
    rs[t] = sum; rq[t] = sq;
    __syncthreads();
    for (int off = 128; off > 0; off >>= 1) {
        if (t < off) { rs[t] += rs[t + off]; rq[t] += rq[t + off]; }
        __syncthreads();
    }
    __shared__ float smean, sinv;
    if (t == 0) {
        float mean = rs[0] * (1.0f / 32768.0f);
        float var  = rq[0] * (1.0f / 32768.0f) - mean * mean;
        smean = mean;
        sinv  = rsqrtf(var + 1e-5f);
    }
    __syncthreads();
    const float mean = smean, inv = sinv;

    for (int idx = t; idx < 4096; idx += 256) {
        int s = idx >> 3, c8 = idx & 7;
        ushort8 v = *reinterpret_cast<const ushort8*>(&base[(size_t)s * QKVLD + c8 * 8]);
        float o[8];
#pragma unroll
        for (int j = 0; j < 8; ++j) {
            float wj = gn_w[g * DHEAD + c8 * 8 + j];
            float bj = gn_b[g * DHEAD + c8 * 8 + j];
            o[j] = (bf2f(v[j]) - mean) * inv * wj + bj;
        }
        float* dst = &out[(size_t)(1 + m * S_SEG + s) * HD + g * DHEAD + c8 * 8];
        *reinterpret_cast<float4*>(dst)     = make_float4(o[0], o[1], o[2], o[3]);
        *reinterpret_cast<float4*>(dst + 4) = make_float4(o[4], o[5], o[6], o[7]);
    }
}

__global__ void zero_row(float* __restrict__ out)
{
    int i = blockIdx.x * 256 + threadIdx.x;
    if (i < HD) out[i] = 0.0f;
}

// ---------------------------------------------------------------------------
extern "C" void kernel_launch(void* const* d_in, const int* in_sizes, int n_in,
                              void* d_out, int out_size, void* d_ws, size_t ws_size,
                              hipStream_t stream)
{
    const float* msg = (const float*)d_in[0];
    const float* Wq  = (const float*)d_in[1];
    const float* Wk  = (const float*)d_in[2];
    const float* Wv  = (const float*)d_in[3];
    const float* Wo  = (const float*)d_in[4];
    const float* bo  = (const float*)d_in[5];
    const float* gnw = (const float*)d_in[6];
    const float* gnb = (const float*)d_in[7];
    float* out = (float*)d_out;

    // d_out scratch (consumed before groupnorm rewrites d_out):
    //   msgb bf16 (67.1 MB) | Abuf fp32 (16.8 MB) | Bc fp32 (16.8 MB)
    u16*   msgb = (u16*)out;
    float* Abuf = out + 16777216;
    float* Bc   = out + 16777216 + 4194304;

    // d_ws: Wb 2 MB (Wq|Wk|Wv|Wo bf16) + qkv 201.3 MB (65536 x 1536).
    // h_mfma overwrites qkv's q-slot with h; EPI gemm writes bf16 res into
    // qkv's k-slot (dead after kv_outer).
    u16* Wb  = (u16*)d_ws;
    u16* qkv = Wb + 4 * 262144;
    u16* resB = qkv + 512;    // res bf16, stride 1536

    convert_weights<<<dim3(128, 4), 256, 0, stream>>>(Wq, Wk, Wv, Wo, Wb);
    convert_bf16<<<16384, 256, 0, stream>>>(msg, msgb, 4194304);

    // fused QKV GEMM: A=msgb (65536x512), B=[Wq;Wk;Wv] (1536x512) -> qkv
    gemm256<0><<<1536, 512, 0, stream>>>(msgb, HD, Wb, qkv, QKVLD, 6, nullptr, nullptr);

    kv_outer<<<dim3(NHEAD, M_SEG), 256, 0, stream>>>(qkv, Abuf);
    scan_kernel<<<128, 256, 0, stream>>>(Abuf, Bc);
    h_mfma<<<dim3(2, M_SEG), 256, 0, stream>>>(qkv, Bc);

    // output GEMM: A=h (qkv q-slot, lda=1536), B=Wo; res=acc+msgb+bias -> bf16
    gemm256<1><<<512, 512, 0, stream>>>(qkv, QKVLD, Wb + 3 * 262144, resB, QKVLD, 2, msgb, bo);

    zero_row<<<2, 256, 0, stream>>>(out);
    groupnorm_bf16<<<dim3(8, M_SEG), 256, 0, stream>>>(resB, out, gnw, gnb);
}